// Round 7
// baseline (62.259 us; speedup 1.0000x reference)
//
#include <hip/hip_runtime.h>

typedef _Float16 f16x8 __attribute__((ext_vector_type(8)));
typedef float    f32x4 __attribute__((ext_vector_type(4)));
typedef float    f32x2 __attribute__((ext_vector_type(2)));

#define NTREES  100
#define WAVES   8
#define NCH     13                     // ceil(100 / 8)
#define BM      32
#define SCALE   144.269504088896f      // 100 * log2(e): z = (h+b)/tau * log2(e)

// LDS map (40960 B -> 3 blocks/CU = 24 waves/CU = 6 waves/SIMD):
//  [0,    8192)  A fragments (f16): [(rt*4+ks)*64 + lane] * 16B, MFMA operand order
//  [8192, 40960) z slices: wave w owns 4096 B at 8192 + w*4096
//                layout [row 32][col 32] f32, byte = (row*128 + col*4) ^ ((row&7)<<4)
//                cols are PERMUTED nodes: 0 = +root, 1..15 = left-subtree BFS,
//                16 = -root (negated dup), 17..31 = right-subtree BFS
#define H_OFF   8192
#define LDS_BYTES (H_OFF + WAVES * 4096)

__device__ __forceinline__ float exp2_fast(float v) {
#if __has_builtin(__builtin_amdgcn_exp2f)
  return __builtin_amdgcn_exp2f(v);
#else
  return exp2f(v);
#endif
}

// sigma pair in base-2 domain: sl = 1/(1+2^-z), sr = 1 - sl
__device__ __forceinline__ void sig2(float z, float& sl, float& sr) {
  z = fmaxf(z, -24.0f);
  float e = exp2_fast(-z);
  sl = __builtin_amdgcn_rcpf(1.0f + e);
  sr = e * sl;
}

// storage col -> (global node, sign): col0=+root, 1..15 left BFS, 16=-root, 17..31 right BFS
__device__ __forceinline__ int node_perm(int sc, float& sg) {
  const int half = sc >> 4, c = sc & 15;
  sg = 1.0f;
  if (c == 0) { if (half) sg = -1.0f; return 0; }
  if (c == 1) return 1 + half;
  if (c < 4)  return 1 + 2 * half + c;      // 3 + 2h + (c-2)
  if (c < 8)  return 3 + 4 * half + c;      // 7 + 4h + (c-4)
  return 7 + 8 * half + c;                  // 15 + 8h + (c-8)
}

// kernel[T][128][31] f32 -> per-lane f16 fragments in permuted/signed col order; bias table too
__global__ void prep_b(const float* __restrict__ kern, const float* __restrict__ bias,
                       unsigned short* __restrict__ bws, float* __restrict__ bias_s) {
  __shared__ float kt[128][33];
  const int t = blockIdx.x, tid = threadIdx.x;
  const float* src = kern + (size_t)t * (128 * 31);
  for (int i = tid; i < 128 * 32; i += 256) {
    const int f = i >> 5, sc = i & 31;
    float sg; const int g = node_perm(sc, sg);
    kt[f][sc] = src[f * 31 + g] * (SCALE * sg);
  }
  if (tid < 32) {
    float sg; const int g = node_perm(tid, sg);
    bias_s[t * 32 + tid] = bias[t * 31 + g] * (SCALE * sg);
  }
  __syncthreads();
  // per tree: 4096 shorts; idx = ks*1024 + fr*512 + lane*8 + j
  // fr 0/1 = cols (lane&15) / 16+(lane&15); k = ks*32 + (lane>>4)*8 + j
  unsigned short* dst = bws + (size_t)t * 4096;
  for (int s = tid; s < 512; s += 256) {
    const int ks = s >> 7, fr = (s >> 6) & 1, lane = s & 63;
    const int n  = (fr << 4) + (lane & 15);
    const int k0 = ks * 32 + ((lane >> 4) << 3);
    f16x8 o;
    #pragma unroll
    for (int j = 0; j < 8; ++j) o[j] = (_Float16)kt[k0 + j][n];
    *(f16x8*)(dst + s * 8) = o;
  }
}

__global__ __launch_bounds__(512, 6) void gbm_main(
    const float* __restrict__ x,
    const unsigned short* __restrict__ bws,
    const float* __restrict__ bias_s,
    const float* __restrict__ leaf,
    float* __restrict__ out)
{
  __shared__ __align__(16) unsigned char lds[LDS_BYTES];
  float* red = (float*)lds;

  const int tid  = threadIdx.x;
  const int lane = tid & 63;
  const int w    = tid >> 6;                 // wave id = tree slot in chunk
  const int rowbase = blockIdx.x * BM;

  // ---- prologue: stage 32 x-rows as f16 MFMA fragments (all 8 waves cooperate) ----
  {
    const int row = tid >> 4;                // 0..31
    const int k   = (tid & 15) << 3;         // 0..120
    const float* px = x + (size_t)(rowbase + row) * 128 + k;
    float4 v0 = *(const float4*)px;
    float4 v1 = *(const float4*)(px + 4);
    float vals[8] = {v0.x, v0.y, v0.z, v0.w, v1.x, v1.y, v1.z, v1.w};
    f16x8 h8;
    #pragma unroll
    for (int j = 0; j < 8; ++j) h8[j] = (_Float16)vals[j];
    const int frag = ((row >> 4) << 2) + (k >> 5);
    const int lnn  = (row & 15) + (((k >> 3) & 3) << 4);
    *(f16x8*)(lds + (frag * 64 + lnn) * 16) = h8;
  }

  // ---- loop-invariant addresses ----
  const int abase = lane * 16;               // A fragment base
  const int hc = lane & 15, hr = (lane >> 4) << 2;
  int wb[4][2];                              // z-write bases (rt via +2048 imm)
  #pragma unroll
  for (int r = 0; r < 4; ++r)
    #pragma unroll
    for (int ct = 0; ct < 2; ++ct)
      wb[r][ct] = H_OFF + (w << 12) + ((hr + r) << 7) +
                  (((ct << 6) + (hc << 2)) ^ (((hr + r) & 7) << 4));
  const int rrow = lane & 31, rhalf = lane >> 5;   // 2 lanes per row
  int rb[4];                                 // z-read addrs (cols 4g..4g+3 of own half)
  #pragma unroll
  for (int g = 0; g < 4; ++g)
    rb[g] = H_OFF + (w << 12) + (rrow << 7) +
            (((rhalf << 6) + (g << 4)) ^ ((rrow & 7) << 4));

  __syncthreads();   // A fragments visible; only barrier until the final reduce

  float outAcc = 0.0f;

  for (int c = 0; c < NCH; ++c) {
    const int tree = c * WAVES + w;
    const bool act = tree < NTREES;          // wave-uniform
    const int tt = act ? tree : (NTREES - 1);

    // ---- B fragments for this tree (L2-resident; TLP hides latency) ----
    f16x8 breg[8];
    const unsigned short* bt = bws + (size_t)tt * 4096;
    #pragma unroll
    for (int i = 0; i < 8; ++i)
      breg[i] = *(const f16x8*)(bt + (size_t)i * 512 + lane * 8);

    const float bv0 = bias_s[tt * 32 + hc];
    const float bv1 = bias_s[tt * 32 + 16 + hc];

    if (act) {
      // ---- single-pass f16 GEMM: 32 rows x 32 cols x 128k ----
      f32x4 acc[2][2] = {};
      __builtin_amdgcn_s_setprio(1);
      #pragma unroll
      for (int ks = 0; ks < 4; ++ks) {
        f16x8 b0 = breg[ks * 2], b1 = breg[ks * 2 + 1];
        #pragma unroll
        for (int rt = 0; rt < 2; ++rt) {
          f16x8 ah = *(const f16x8*)(lds + abase + (rt * 4 + ks) * 1024);
          acc[rt][0] = __builtin_amdgcn_mfma_f32_16x16x32_f16(ah, b0, acc[rt][0], 0, 0, 0);
          acc[rt][1] = __builtin_amdgcn_mfma_f32_16x16x32_f16(ah, b1, acc[rt][1], 0, 0, 0);
        }
      }
      __builtin_amdgcn_s_setprio(0);

      // ---- add bias, scatter z (f32) to wave-private swizzled slice ----
      #pragma unroll
      for (int rt = 0; rt < 2; ++rt)
        #pragma unroll
        for (int ct = 0; ct < 2; ++ct)
          #pragma unroll
          for (int r = 0; r < 4; ++r)
            *(float*)(lds + wb[r][ct] + rt * 2048) = acc[rt][ct][r] + (ct ? bv1 : bv0);

      // ---- read own half-row: cols 0-7 first, eval, then 8-15 ----
      f32x4 h0 = *(const f32x4*)(lds + rb[0]);
      f32x4 h1 = *(const f32x4*)(lds + rb[1]);

      float sl, sr;
      sig2(h0[0], sl, sr);                    // ±root: prob of entering this half
      const float c0 = sl;
      sig2(h0[1], sl, sr);
      const float a0 = c0 * sl, a1 = c0 * sr;
      sig2(h0[2], sl, sr);
      const float b0_ = a0 * sl, b1_ = a0 * sr;
      sig2(h0[3], sl, sr);
      const float b2_ = a1 * sl, b3_ = a1 * sr;
      float cum[8];
      sig2(h1[0], sl, sr); cum[0] = b0_ * sl; cum[1] = b0_ * sr;
      sig2(h1[1], sl, sr); cum[2] = b1_ * sl; cum[3] = b1_ * sr;
      sig2(h1[2], sl, sr); cum[4] = b2_ * sl; cum[5] = b2_ * sr;
      sig2(h1[3], sl, sr); cum[6] = b3_ * sl; cum[7] = b3_ * sr;

      f32x4 h2 = *(const f32x4*)(lds + rb[2]);
      f32x4 h3 = *(const f32x4*)(lds + rb[3]);
      const f32x2* lp2 = (const f32x2*)(leaf + (size_t)tree * 32 + (rhalf << 4));

      float s = 0.0f;
      #pragma unroll
      for (int i = 0; i < 4; ++i) {
        sig2(h2[i], sl, sr);
        f32x2 lv = lp2[i];
        s = fmaf(cum[i], fmaf(sl, lv[0], sr * lv[1]), s);
      }
      #pragma unroll
      for (int i = 0; i < 4; ++i) {
        sig2(h3[i], sl, sr);
        f32x2 lv = lp2[4 + i];
        s = fmaf(cum[4 + i], fmaf(sl, lv[0], sr * lv[1]), s);
      }
      outAcc += s;
    }
  }

  // ---- reduce 16 partials (8 waves x 2 halves) per row, write out ----
  __syncthreads();
  red[tid] = outAcc;
  __syncthreads();
  if (tid < 32) {
    float s = 0.0f;
    #pragma unroll
    for (int j = 0; j < 16; ++j)
      s += red[j * 32 + tid];
    out[rowbase + tid] = s;
  }
}

extern "C" void kernel_launch(void* const* d_in, const int* in_sizes, int n_in,
                              void* d_out, int out_size, void* d_ws, size_t ws_size,
                              hipStream_t stream) {
  const float* x    = (const float*)d_in[0];
  const float* kern = (const float*)d_in[1];
  const float* bias = (const float*)d_in[2];
  const float* leaf = (const float*)d_in[3];
  // d_in[4] = route: topology hard-coded (perfect depth-5 tree, bit0=left)

  unsigned short* bws = (unsigned short*)d_ws;              // 100*4096 shorts = 819200 B
  float* bias_s = (float*)((unsigned char*)d_ws + 819200);  // 100*32 f32 = 12800 B

  prep_b<<<NTREES, 256, 0, stream>>>(kern, bias, bws, bias_s);
  gbm_main<<<32768 / BM, 512, 0, stream>>>(x, bws, bias_s, leaf, (float*)d_out);
}

// Round 8
// 60.653 us; speedup vs baseline: 1.0265x; 1.0265x over previous
//
#include <hip/hip_runtime.h>

typedef _Float16 f16x8  __attribute__((ext_vector_type(8)));
typedef float    f32x16 __attribute__((ext_vector_type(16)));
typedef float    f32x4  __attribute__((ext_vector_type(4)));

#define NTREES  100
#define WAVES   8
#define NCH     13                    // ceil(100 / 8)
#define BM      32
#define KS      9                     // 8 real k-steps + 1 bias k-step
#define TSTRIDE (KS * 512)            // shorts per tree in ws (4608)
#define SCALE   144.269504088896f     // 100 * log2(e): z = (h+b)/tau * log2(e)

// ---- tree <-> register geometry ------------------------------------------
// D = Tree(A) x X^T(B) via mfma_f32_32x32x16_f16:
//   D[srow][xrow]: xrow = lane&31, srow = (reg&3) + 8*(reg>>2) + 4*(lane>>5)
// We choose the storage-row permutation so that reg means:
//   reg 0 = ±root (sign - for hi half), reg 1 = level1 node of own half,
//   reg 2-3 = level2, reg 4-7 = level3, reg 8-15 = level4 (BFS within half).
// Lane (xrow, half) therefore holds its full 16-node half-tree in acc regs.
__device__ __forceinline__ int node_of_row(int sr, float& sg) {
  const int h   = (sr >> 2) & 1;
  const int reg = (sr & 3) + ((sr >> 3) << 2);
  sg = 1.0f;
  if (reg == 0) { if (h) sg = -1.0f; return 0; }
  if (reg == 1) return 1 + h;
  if (reg < 4)  return 1 + 2 * h + reg;
  if (reg < 8)  return 3 + 4 * h + reg;
  return 7 + 8 * h + reg;
}

__device__ __forceinline__ float exp2_fast(float v) {
#if __has_builtin(__builtin_amdgcn_exp2f)
  return __builtin_amdgcn_exp2f(v);
#else
  return exp2f(v);
#endif
}

// sl = sigma(z) = 1/(1+2^-z), sr = 1-sl.  Saturation-safe without clamps:
// e=inf -> sl=0,sr=1; e=0 -> sl=1,sr=0.
__device__ __forceinline__ void sig2(float z, float& sl, float& sr) {
  float e = exp2_fast(-z);
  sl = __builtin_amdgcn_rcpf(1.0f + e);
  sr = 1.0f - sl;
}

// kernel[T][128][31] f32 (+bias) -> A-operand fragments, permuted/signed/scaled.
// Per tree t: TSTRIDE shorts; frag idx = ks*512 + lane*8 + j holds
// A[row = lane&31][k = ks*16 + (lane>>5)*8 + j]; k==128 column = bias.
__global__ void prep_b(const float* __restrict__ kern, const float* __restrict__ bias,
                       unsigned short* __restrict__ bws) {
  __shared__ float kt[128][32];
  __shared__ float bs[32];
  const int t = blockIdx.x, tid = threadIdx.x;
  const float* src = kern + (size_t)t * (128 * 31);
  for (int i = tid; i < 128 * 32; i += 256) {
    const int f = i >> 5, sr_ = i & 31;
    float sg; const int g = node_of_row(sr_, sg);
    kt[f][sr_] = src[f * 31 + g] * (SCALE * sg);
  }
  if (tid < 32) {
    float sg; const int g = node_of_row(tid, sg);
    bs[tid] = bias[t * 31 + g] * (SCALE * sg);
  }
  __syncthreads();
  unsigned short* dst = bws + (size_t)t * TSTRIDE;
  for (int s = tid; s < KS * 64; s += 256) {
    const int ks = s >> 6, lane = s & 63;
    const int row = lane & 31;
    const int k0 = ks * 16 + ((lane >> 5) << 3);
    f16x8 o;
    if (ks < 8) {
      #pragma unroll
      for (int j = 0; j < 8; ++j) o[j] = (_Float16)kt[k0 + j][row];
    } else {
      #pragma unroll
      for (int j = 0; j < 8; ++j) o[j] = (_Float16)0.0f;
      if (lane < 32) o[0] = (_Float16)bs[row];       // k==128 -> bias column
    }
    *(f16x8*)(dst + s * 8) = o;
  }
}

__global__ __launch_bounds__(512, 4) void gbm_main(
    const float* __restrict__ x,
    const unsigned short* __restrict__ bws,
    const float* __restrict__ leaf,
    float* __restrict__ out)
{
  // LDS: x as B-operand frags [ks 9][lane 64] * 16B = 9216 B (reduction overlays)
  __shared__ __align__(16) unsigned char lds[KS * 64 * 16];
  float* red = (float*)lds;

  const int tid  = threadIdx.x;
  const int lane = tid & 63;
  const int w    = tid >> 6;                 // wave id = tree slot in chunk
  const int rowbase = blockIdx.x * BM;

  // ---- stage x as B-operand fragments: B[k][col=xrow], k=ks*16+(lane>>5)*8+j;
  //      ks==8 is the constant-1 bias feature (k=128) ----
  for (int s = tid; s < KS * 64; s += 512) {
    const int ks = s >> 6, l = s & 63;
    f16x8 h8;
    if (ks < 8) {
      const int xrow = l & 31;
      const int k0 = ks * 16 + ((l >> 5) << 3);
      const float* px = x + (size_t)(rowbase + xrow) * 128 + k0;
      float4 v0 = *(const float4*)px;
      float4 v1 = *(const float4*)(px + 4);
      h8[0] = (_Float16)v0.x; h8[1] = (_Float16)v0.y;
      h8[2] = (_Float16)v0.z; h8[3] = (_Float16)v0.w;
      h8[4] = (_Float16)v1.x; h8[5] = (_Float16)v1.y;
      h8[6] = (_Float16)v1.z; h8[7] = (_Float16)v1.w;
    } else {
      #pragma unroll
      for (int j = 0; j < 8; ++j) h8[j] = (_Float16)0.0f;
      if (l < 32) h8[0] = (_Float16)1.0f;            // B[128][col] = 1 for all cols
    }
    *(f16x8*)(lds + s * 16) = h8;
  }

  // ---- preload chunk 0 tree fragments ----
  f16x8 br[KS];
  {
    const unsigned short* bt = bws + (size_t)w * TSTRIDE;
    #pragma unroll
    for (int i = 0; i < KS; ++i)
      br[i] = *(const f16x8*)(bt + (size_t)i * 512 + lane * 8);
  }

  __syncthreads();   // x fragments visible; only barrier until the final reduce

  const int h = lane >> 5;                   // which half-tree this lane owns
  float outAcc = 0.0f;

  for (int c = 0; c < NCH; ++c) {
    const int tree = c * WAVES + w;
    const bool act = tree < NTREES;          // wave-uniform

    f32x16 acc = {};
    if (act) {
      __builtin_amdgcn_s_setprio(1);
      #pragma unroll
      for (int ks = 0; ks < KS; ++ks) {
        f16x8 bx = *(const f16x8*)(lds + (ks * 64 + lane) * 16);
        acc = __builtin_amdgcn_mfma_f32_32x32x16_f16(br[ks], bx, acc, 0, 0, 0);
      }
      __builtin_amdgcn_s_setprio(0);
    }

    // ---- issue next chunk's tree loads (WAR orders after MFMAs; eval hides L2) ----
    if ((c + 1) * WAVES + w < NTREES) {
      const unsigned short* nb = bws + (size_t)((c + 1) * WAVES + w) * TSTRIDE;
      #pragma unroll
      for (int i = 0; i < KS; ++i)
        br[i] = *(const f16x8*)(nb + (size_t)i * 512 + lane * 8);
    }

    if (act) {
      // ---- leaf values for own half (broadcast within half, L2-resident) ----
      const float* lp = leaf + (size_t)tree * 32 + (h << 4);
      f32x4 L0 = *(const f32x4*)lp;
      f32x4 L1 = *(const f32x4*)(lp + 4);
      f32x4 L2 = *(const f32x4*)(lp + 8);
      f32x4 L3 = *(const f32x4*)(lp + 12);

      // ---- half-tree eval straight from acc regs (z includes bias) ----
      float sl, sr;
      sig2(acc[0], sl, sr); const float c0 = sl;            // ±root
      sig2(acc[1], sl, sr); const float a0 = c0 * sl, a1 = c0 * sr;
      sig2(acc[2], sl, sr); const float b0 = a0 * sl, b1 = a0 * sr;
      sig2(acc[3], sl, sr); const float b2 = a1 * sl, b3 = a1 * sr;
      float cum[8];
      sig2(acc[4], sl, sr); cum[0] = b0 * sl; cum[1] = b0 * sr;
      sig2(acc[5], sl, sr); cum[2] = b1 * sl; cum[3] = b1 * sr;
      sig2(acc[6], sl, sr); cum[4] = b2 * sl; cum[5] = b2 * sr;
      sig2(acc[7], sl, sr); cum[6] = b3 * sl; cum[7] = b3 * sr;

      float s = 0.0f;
      sig2(acc[8],  sl, sr); s = fmaf(cum[0], fmaf(sl, L0[0], sr * L0[1]), s);
      sig2(acc[9],  sl, sr); s = fmaf(cum[1], fmaf(sl, L0[2], sr * L0[3]), s);
      sig2(acc[10], sl, sr); s = fmaf(cum[2], fmaf(sl, L1[0], sr * L1[1]), s);
      sig2(acc[11], sl, sr); s = fmaf(cum[3], fmaf(sl, L1[2], sr * L1[3]), s);
      sig2(acc[12], sl, sr); s = fmaf(cum[4], fmaf(sl, L2[0], sr * L2[1]), s);
      sig2(acc[13], sl, sr); s = fmaf(cum[5], fmaf(sl, L2[2], sr * L2[3]), s);
      sig2(acc[14], sl, sr); s = fmaf(cum[6], fmaf(sl, L3[0], sr * L3[1]), s);
      sig2(acc[15], sl, sr); s = fmaf(cum[7], fmaf(sl, L3[2], sr * L3[3]), s);
      outAcc += s;
    }
  }

  // ---- reduce 16 partials (8 waves x 2 halves) per row, write out ----
  __syncthreads();
  red[tid] = outAcc;
  __syncthreads();
  if (tid < 32) {
    float s = 0.0f;
    #pragma unroll
    for (int j = 0; j < 16; ++j)
      s += red[j * 32 + tid];
    out[rowbase + tid] = s;
  }
}

extern "C" void kernel_launch(void* const* d_in, const int* in_sizes, int n_in,
                              void* d_out, int out_size, void* d_ws, size_t ws_size,
                              hipStream_t stream) {
  const float* x    = (const float*)d_in[0];
  const float* kern = (const float*)d_in[1];
  const float* bias = (const float*)d_in[2];
  const float* leaf = (const float*)d_in[3];
  // d_in[4] = route: topology hard-coded (perfect depth-5 tree, bit0=left)

  unsigned short* bws = (unsigned short*)d_ws;   // 100 * 4608 shorts = 921600 B

  prep_b<<<NTREES, 256, 0, stream>>>(kern, bias, bws);
  gbm_main<<<32768 / BM, 512, 0, stream>>>(x, bws, leaf, (float*)d_out);
}

// Round 10
// 52.349 us; speedup vs baseline: 1.1893x; 1.1586x over previous
//
#include <hip/hip_runtime.h>

typedef _Float16 f16x8  __attribute__((ext_vector_type(8)));
typedef float    f32x16 __attribute__((ext_vector_type(16)));
typedef float    f32x4  __attribute__((ext_vector_type(4)));

#define NTREES  100
#define WAVES   8
#define NCH     13                    // ceil(100 / 8)
#define BM      64                    // two 32-row x-tiles per block
#define KS      9                     // 8 real k-steps + 1 bias k-step
#define TSTRIDE (KS * 512)            // shorts per tree in ws (4608)
#define NSCALE  (-144.269504088896f)  // -(100*log2 e): acc = -z, exp2 needs no negate

// ---- tree <-> register geometry (verified R8) -----------------------------
// D = Tree(A) x X^T(B) via mfma_f32_32x32x16_f16:
//   D[srow][xrow]: xrow = lane&31, srow = (reg&3) + 8*(reg>>2) + 4*(lane>>5)
// storage-row permutation: reg 0 = ±root (sign flips for hi half), reg 1 = L1
// node of own half, reg 2-3 = L2, reg 4-7 = L3, reg 8-15 = L4 (BFS in half).
__device__ __forceinline__ int node_of_row(int sr, float& sg) {
  const int h   = (sr >> 2) & 1;
  const int reg = (sr & 3) + ((sr >> 3) << 2);
  sg = 1.0f;
  if (reg == 0) { if (h) sg = -1.0f; return 0; }
  if (reg == 1) return 1 + h;
  if (reg < 4)  return 1 + 2 * h + reg;
  if (reg < 8)  return 3 + 4 * h + reg;
  return 7 + 8 * h + reg;
}

__device__ __forceinline__ float exp2_fast(float v) {
#if __has_builtin(__builtin_amdgcn_exp2f)
  return __builtin_amdgcn_exp2f(v);
#else
  return exp2f(v);
#endif
}

// acc holds -z (base-2 scaled): sigma(z) = 1/(1 + 2^-z) = rcp(1 + exp2(acc))
__device__ __forceinline__ float sigl(float zn) {
  float e = exp2_fast(zn);
  return __builtin_amdgcn_rcpf(1.0f + e);
}

// kernel/bias -> negated, permuted, scaled A-operand fragments (d_ws only)
__global__ void prep_b(const float* __restrict__ kern, const float* __restrict__ bias,
                       unsigned short* __restrict__ bws) {
  __shared__ float kt[128][32];
  __shared__ float bs[32];
  const int t = blockIdx.x, tid = threadIdx.x;
  const float* src = kern + (size_t)t * (128 * 31);
  for (int i = tid; i < 128 * 32; i += 256) {
    const int f = i >> 5, sr_ = i & 31;
    float sg; const int g = node_of_row(sr_, sg);
    kt[f][sr_] = src[f * 31 + g] * (NSCALE * sg);
  }
  if (tid < 32) {
    float sg; const int g = node_of_row(tid, sg);
    bs[tid] = bias[t * 31 + g] * (NSCALE * sg);
  }
  __syncthreads();
  unsigned short* dst = bws + (size_t)t * TSTRIDE;
  for (int s = tid; s < KS * 64; s += 256) {
    const int ks = s >> 6, lane = s & 63;
    const int row = lane & 31;
    const int k0 = ks * 16 + ((lane >> 5) << 3);
    f16x8 o;
    if (ks < 8) {
      #pragma unroll
      for (int j = 0; j < 8; ++j) o[j] = (_Float16)kt[k0 + j][row];
    } else {
      #pragma unroll
      for (int j = 0; j < 8; ++j) o[j] = (_Float16)0.0f;
      if (lane < 32) o[0] = (_Float16)bs[row];    // k==128 -> bias column
    }
    *(f16x8*)(dst + s * 8) = o;
  }
}

// full half-tree eval from acc regs; L* = leaf pairs (Ll,Lr) per leaf node
__device__ __forceinline__ float half_eval(const f32x16& a, const f32x4& L0,
                                           const f32x4& L1, const f32x4& L2,
                                           const f32x4& L3) {
  float sl, sr;
  const float c0 = sigl(a[0]);                           // ±root
  sl = sigl(a[1]); sr = 1.0f - sl;
  const float a0 = c0 * sl, a1 = c0 * sr;
  sl = sigl(a[2]); sr = 1.0f - sl;
  const float b0 = a0 * sl, b1 = a0 * sr;
  sl = sigl(a[3]); sr = 1.0f - sl;
  const float b2 = a1 * sl, b3 = a1 * sr;
  float cum[8];
  sl = sigl(a[4]); sr = 1.0f - sl; cum[0] = b0 * sl; cum[1] = b0 * sr;
  sl = sigl(a[5]); sr = 1.0f - sl; cum[2] = b1 * sl; cum[3] = b1 * sr;
  sl = sigl(a[6]); sr = 1.0f - sl; cum[4] = b2 * sl; cum[5] = b2 * sr;
  sl = sigl(a[7]); sr = 1.0f - sl; cum[6] = b3 * sl; cum[7] = b3 * sr;
  // leaf level: value = sl*Ll + (1-sl)*Lr = fmaf(sl, Ll-Lr, Lr)
  float s = 0.0f;
  s = fmaf(cum[0], fmaf(sigl(a[8]),  L0[0] - L0[1], L0[1]), s);
  s = fmaf(cum[1], fmaf(sigl(a[9]),  L0[2] - L0[3], L0[3]), s);
  s = fmaf(cum[2], fmaf(sigl(a[10]), L1[0] - L1[1], L1[1]), s);
  s = fmaf(cum[3], fmaf(sigl(a[11]), L1[2] - L1[3], L1[3]), s);
  s = fmaf(cum[4], fmaf(sigl(a[12]), L2[0] - L2[1], L2[1]), s);
  s = fmaf(cum[5], fmaf(sigl(a[13]), L2[2] - L2[3], L2[3]), s);
  s = fmaf(cum[6], fmaf(sigl(a[14]), L3[0] - L3[1], L3[1]), s);
  s = fmaf(cum[7], fmaf(sigl(a[15]), L3[2] - L3[3], L3[3]), s);
  return s;
}

__global__ __launch_bounds__(512, 4) void gbm_main(
    const float* __restrict__ x,
    const unsigned short* __restrict__ bws,
    const float* __restrict__ leaf,
    float* __restrict__ out)
{
  // LDS: x B-operand frags, 2 tiles x [ks 9][lane 64] x 16B = 18432 B
  __shared__ __align__(16) unsigned char lds[2 * KS * 64 * 16];
  float* red = (float*)lds;

  const int tid  = threadIdx.x;
  const int lane = tid & 63;
  const int w    = tid >> 6;                 // wave id = tree slot in chunk
  const int rowbase = blockIdx.x * BM;

  // ---- stage both x tiles as B-operand fragments; ks==8 = const-1 bias feat ----
  #pragma unroll
  for (int T = 0; T < 2; ++T)
    for (int s = tid; s < KS * 64; s += 512) {
      const int ks = s >> 6, l = s & 63;
      f16x8 h8;
      if (ks < 8) {
        const int xrow = (l & 31) + T * 32;
        const int k0 = ks * 16 + ((l >> 5) << 3);
        const float* px = x + (size_t)(rowbase + xrow) * 128 + k0;
        float4 v0 = *(const float4*)px;
        float4 v1 = *(const float4*)(px + 4);
        h8[0] = (_Float16)v0.x; h8[1] = (_Float16)v0.y;
        h8[2] = (_Float16)v0.z; h8[3] = (_Float16)v0.w;
        h8[4] = (_Float16)v1.x; h8[5] = (_Float16)v1.y;
        h8[6] = (_Float16)v1.z; h8[7] = (_Float16)v1.w;
      } else {
        #pragma unroll
        for (int j = 0; j < 8; ++j) h8[j] = (_Float16)0.0f;
        if (l < 32) h8[0] = (_Float16)1.0f;
      }
      *(f16x8*)(lds + T * (KS * 64 * 16) + s * 16) = h8;
    }

  // ---- preload chunk 0 tree fragments ----
  f16x8 br[KS];
  {
    const unsigned short* bt = bws + (size_t)w * TSTRIDE;
    #pragma unroll
    for (int i = 0; i < KS; ++i)
      br[i] = *(const f16x8*)(bt + (size_t)i * 512 + lane * 8);
  }

  __syncthreads();   // x fragments visible; only barrier until the final reduce

  const int h = lane >> 5;                   // which half-tree this lane owns
  float outAcc0 = 0.0f, outAcc1 = 0.0f;

  for (int c = 0; c < NCH; ++c) {
    const int tree = c * WAVES + w;
    const bool act = tree < NTREES;          // wave-uniform

    f32x16 acc0 = {}, acc1 = {};
    if (act) {
      __builtin_amdgcn_s_setprio(1);
      #pragma unroll
      for (int ks = 0; ks < KS; ++ks) {
        f16x8 bx0 = *(const f16x8*)(lds + (ks * 64 + lane) * 16);
        f16x8 bx1 = *(const f16x8*)(lds + KS * 64 * 16 + (ks * 64 + lane) * 16);
        acc0 = __builtin_amdgcn_mfma_f32_32x32x16_f16(br[ks], bx0, acc0, 0, 0, 0);
        acc1 = __builtin_amdgcn_mfma_f32_32x32x16_f16(br[ks], bx1, acc1, 0, 0, 0);
      }
      __builtin_amdgcn_s_setprio(0);
    }

    // ---- issue next chunk's tree loads (WAR orders after MFMAs; eval hides L2) ----
    if ((c + 1) * WAVES + w < NTREES) {
      const unsigned short* nb = bws + (size_t)((c + 1) * WAVES + w) * TSTRIDE;
      #pragma unroll
      for (int i = 0; i < KS; ++i)
        br[i] = *(const f16x8*)(nb + (size_t)i * 512 + lane * 8);
    }

    if (act) {
      const float* lp = leaf + (size_t)tree * 32 + (h << 4);   // own half's 16 leaves
      f32x4 L0 = *(const f32x4*)lp;
      f32x4 L1 = *(const f32x4*)(lp + 4);
      f32x4 L2 = *(const f32x4*)(lp + 8);
      f32x4 L3 = *(const f32x4*)(lp + 12);

      outAcc0 += half_eval(acc0, L0, L1, L2, L3);
      outAcc1 += half_eval(acc1, L0, L1, L2, L3);
    }
  }

  // ---- reduce 16 partials (8 waves x 2 halves) per row for both tiles ----
  __syncthreads();
  red[tid] = outAcc0;
  red[512 + tid] = outAcc1;
  __syncthreads();
  if (tid < BM) {
    const int tile = tid >> 5, r = tid & 31;
    float s = 0.0f;
    #pragma unroll
    for (int j = 0; j < 16; ++j)
      s += red[tile * 512 + j * 32 + r];
    out[rowbase + tid] = s;
  }
}

extern "C" void kernel_launch(void* const* d_in, const int* in_sizes, int n_in,
                              void* d_out, int out_size, void* d_ws, size_t ws_size,
                              hipStream_t stream) {
  const float* x    = (const float*)d_in[0];
  const float* kern = (const float*)d_in[1];
  const float* bias = (const float*)d_in[2];
  const float* leaf = (const float*)d_in[3];
  // d_in[4] = route: topology hard-coded (perfect depth-5 tree, bit0=left)

  unsigned short* bws = (unsigned short*)d_ws;   // 100*4608 shorts = 921600 B

  prep_b<<<NTREES, 256, 0, stream>>>(kern, bias, bws);
  gbm_main<<<32768 / BM, 512, 0, stream>>>(x, bws, leaf, (float*)d_out);
}

// Round 11
// 51.804 us; speedup vs baseline: 1.2018x; 1.0105x over previous
//
#include <hip/hip_runtime.h>

typedef _Float16 f16x8  __attribute__((ext_vector_type(8)));
typedef float    f32x16 __attribute__((ext_vector_type(16)));
typedef float    f32x4  __attribute__((ext_vector_type(4)));

#define NTREES  100
#define WAVES   8
#define NCH     13                    // ceil(100 / 8)
#define BM      128                   // four 32-row x-tiles per block
#define NT      4                     // tiles per wave-chunk
#define KS      9                     // 8 real k-steps + 1 bias k-step
#define TSTRIDE (KS * 512)            // shorts per tree in ws (4608)
#define NSCALE  (-144.269504088896f)  // -(100*log2 e): acc = -z, exp2 needs no negate

// ---- tree <-> register geometry (verified R8/R10) -------------------------
// D = Tree(A) x X^T(B) via mfma_f32_32x32x16_f16:
//   D[srow][xrow]: xrow = lane&31, srow = (reg&3) + 8*(reg>>2) + 4*(lane>>5)
// storage-row permutation: reg 0 = ±root (sign flips for hi half), reg 1 = L1
// node of own half, reg 2-3 = L2, reg 4-7 = L3, reg 8-15 = L4 (BFS in half).
__device__ __forceinline__ int node_of_row(int sr, float& sg) {
  const int h   = (sr >> 2) & 1;
  const int reg = (sr & 3) + ((sr >> 3) << 2);
  sg = 1.0f;
  if (reg == 0) { if (h) sg = -1.0f; return 0; }
  if (reg == 1) return 1 + h;
  if (reg < 4)  return 1 + 2 * h + reg;
  if (reg < 8)  return 3 + 4 * h + reg;
  return 7 + 8 * h + reg;
}

__device__ __forceinline__ float exp2_fast(float v) {
#if __has_builtin(__builtin_amdgcn_exp2f)
  return __builtin_amdgcn_exp2f(v);
#else
  return exp2f(v);
#endif
}

// acc holds -z (base-2 scaled): sigma(z) = 1/(1 + 2^-z) = rcp(1 + exp2(acc))
__device__ __forceinline__ float sigl(float zn) {
  float e = exp2_fast(zn);
  return __builtin_amdgcn_rcpf(1.0f + e);
}

// kernel/bias -> negated, permuted, scaled A-operand fragments (d_ws only)
__global__ void prep_b(const float* __restrict__ kern, const float* __restrict__ bias,
                       unsigned short* __restrict__ bws) {
  __shared__ float kt[128][32];
  __shared__ float bs[32];
  const int t = blockIdx.x, tid = threadIdx.x;
  const float* src = kern + (size_t)t * (128 * 31);
  for (int i = tid; i < 128 * 32; i += 512) {
    const int f = i >> 5, sr_ = i & 31;
    float sg; const int g = node_of_row(sr_, sg);
    kt[f][sr_] = src[f * 31 + g] * (NSCALE * sg);
  }
  if (tid < 32) {
    float sg; const int g = node_of_row(tid, sg);
    bs[tid] = bias[t * 31 + g] * (NSCALE * sg);
  }
  __syncthreads();
  unsigned short* dst = bws + (size_t)t * TSTRIDE;
  for (int s = tid; s < KS * 64; s += 512) {
    const int ks = s >> 6, lane = s & 63;
    const int row = lane & 31;
    const int k0 = ks * 16 + ((lane >> 5) << 3);
    f16x8 o;
    if (ks < 8) {
      #pragma unroll
      for (int j = 0; j < 8; ++j) o[j] = (_Float16)kt[k0 + j][row];
    } else {
      #pragma unroll
      for (int j = 0; j < 8; ++j) o[j] = (_Float16)0.0f;
      if (lane < 32) o[0] = (_Float16)bs[row];    // k==128 -> bias column
    }
    *(f16x8*)(dst + s * 8) = o;
  }
}

// full half-tree eval from acc regs; L* = leaf pairs (Ll,Lr) per leaf node
__device__ __forceinline__ float half_eval(const f32x16& a, const f32x4& L0,
                                           const f32x4& L1, const f32x4& L2,
                                           const f32x4& L3) {
  float sl, sr;
  const float c0 = sigl(a[0]);                           // ±root
  sl = sigl(a[1]); sr = 1.0f - sl;
  const float a0 = c0 * sl, a1 = c0 * sr;
  sl = sigl(a[2]); sr = 1.0f - sl;
  const float b0 = a0 * sl, b1 = a0 * sr;
  sl = sigl(a[3]); sr = 1.0f - sl;
  const float b2 = a1 * sl, b3 = a1 * sr;
  float cum[8];
  sl = sigl(a[4]); sr = 1.0f - sl; cum[0] = b0 * sl; cum[1] = b0 * sr;
  sl = sigl(a[5]); sr = 1.0f - sl; cum[2] = b1 * sl; cum[3] = b1 * sr;
  sl = sigl(a[6]); sr = 1.0f - sl; cum[4] = b2 * sl; cum[5] = b2 * sr;
  sl = sigl(a[7]); sr = 1.0f - sl; cum[6] = b3 * sl; cum[7] = b3 * sr;
  // leaf level: value = sl*Ll + (1-sl)*Lr = fmaf(sl, Ll-Lr, Lr)
  float s = 0.0f;
  s = fmaf(cum[0], fmaf(sigl(a[8]),  L0[0] - L0[1], L0[1]), s);
  s = fmaf(cum[1], fmaf(sigl(a[9]),  L0[2] - L0[3], L0[3]), s);
  s = fmaf(cum[2], fmaf(sigl(a[10]), L1[0] - L1[1], L1[1]), s);
  s = fmaf(cum[3], fmaf(sigl(a[11]), L1[2] - L1[3], L1[3]), s);
  s = fmaf(cum[4], fmaf(sigl(a[12]), L2[0] - L2[1], L2[1]), s);
  s = fmaf(cum[5], fmaf(sigl(a[13]), L2[2] - L2[3], L2[3]), s);
  s = fmaf(cum[6], fmaf(sigl(a[14]), L3[0] - L3[1], L3[1]), s);
  s = fmaf(cum[7], fmaf(sigl(a[15]), L3[2] - L3[3], L3[3]), s);
  return s;
}

__global__ __launch_bounds__(512, 2) void gbm_main(
    const float* __restrict__ x,
    const unsigned short* __restrict__ bws,
    const float* __restrict__ leaf,
    float* __restrict__ out)
{
  // LDS: x B-operand frags, NT tiles x [ks 9][lane 64] x 16B = 36864 B
  __shared__ __align__(16) unsigned char lds[NT * KS * 64 * 16];
  float* red = (float*)lds;

  const int tid  = threadIdx.x;
  const int lane = tid & 63;
  const int w    = tid >> 6;                 // wave id = tree slot in chunk
  const int rowbase = blockIdx.x * BM;

  // ---- stage all 4 x tiles as B-operand fragments; ks==8 = const-1 bias feat ----
  #pragma unroll
  for (int T = 0; T < NT; ++T)
    for (int s = tid; s < KS * 64; s += 512) {
      const int ks = s >> 6, l = s & 63;
      f16x8 h8;
      if (ks < 8) {
        const int xrow = (l & 31) + T * 32;
        const int k0 = ks * 16 + ((l >> 5) << 3);
        const float* px = x + (size_t)(rowbase + xrow) * 128 + k0;
        float4 v0 = *(const float4*)px;
        float4 v1 = *(const float4*)(px + 4);
        h8[0] = (_Float16)v0.x; h8[1] = (_Float16)v0.y;
        h8[2] = (_Float16)v0.z; h8[3] = (_Float16)v0.w;
        h8[4] = (_Float16)v1.x; h8[5] = (_Float16)v1.y;
        h8[6] = (_Float16)v1.z; h8[7] = (_Float16)v1.w;
      } else {
        #pragma unroll
        for (int j = 0; j < 8; ++j) h8[j] = (_Float16)0.0f;
        if (l < 32) h8[0] = (_Float16)1.0f;
      }
      *(f16x8*)(lds + T * (KS * 64 * 16) + s * 16) = h8;
    }

  // ---- preload chunk 0 tree fragments ----
  f16x8 br[KS];
  {
    const unsigned short* bt = bws + (size_t)w * TSTRIDE;
    #pragma unroll
    for (int i = 0; i < KS; ++i)
      br[i] = *(const f16x8*)(bt + (size_t)i * 512 + lane * 8);
  }

  __syncthreads();   // x fragments visible; only barrier until the final reduce

  const int h = lane >> 5;                   // which half-tree this lane owns
  float outAcc[NT] = {0.0f, 0.0f, 0.0f, 0.0f};

  for (int c = 0; c < NCH; ++c) {
    const int tree = c * WAVES + w;
    const bool act = tree < NTREES;          // wave-uniform

    f32x16 acc[NT] = {};
    if (act) {
      __builtin_amdgcn_s_setprio(1);
      #pragma unroll
      for (int ks = 0; ks < KS; ++ks) {
        #pragma unroll
        for (int T = 0; T < NT; ++T) {
          f16x8 bx = *(const f16x8*)(lds + T * (KS * 64 * 16) + (ks * 64 + lane) * 16);
          acc[T] = __builtin_amdgcn_mfma_f32_32x32x16_f16(br[ks], bx, acc[T], 0, 0, 0);
        }
      }
      __builtin_amdgcn_s_setprio(0);
    }

    // ---- issue next chunk's tree loads (WAR orders after MFMAs; eval hides L2) ----
    if ((c + 1) * WAVES + w < NTREES) {
      const unsigned short* nb = bws + (size_t)((c + 1) * WAVES + w) * TSTRIDE;
      #pragma unroll
      for (int i = 0; i < KS; ++i)
        br[i] = *(const f16x8*)(nb + (size_t)i * 512 + lane * 8);
    }

    if (act) {
      const float* lp = leaf + (size_t)tree * 32 + (h << 4);   // own half's 16 leaves
      f32x4 L0 = *(const f32x4*)lp;
      f32x4 L1 = *(const f32x4*)(lp + 4);
      f32x4 L2 = *(const f32x4*)(lp + 8);
      f32x4 L3 = *(const f32x4*)(lp + 12);

      #pragma unroll
      for (int T = 0; T < NT; ++T)
        outAcc[T] += half_eval(acc[T], L0, L1, L2, L3);
    }
  }

  // ---- reduce 16 partials (8 waves x 2 halves) per row for all 4 tiles ----
  __syncthreads();
  #pragma unroll
  for (int T = 0; T < NT; ++T)
    red[T * 512 + tid] = outAcc[T];
  __syncthreads();
  if (tid < BM) {
    const int tile = tid >> 5, r = tid & 31;
    float s = 0.0f;
    #pragma unroll
    for (int j = 0; j < 16; ++j)
      s += red[tile * 512 + j * 32 + r];
    out[rowbase + tid] = s;
  }
}

extern "C" void kernel_launch(void* const* d_in, const int* in_sizes, int n_in,
                              void* d_out, int out_size, void* d_ws, size_t ws_size,
                              hipStream_t stream) {
  const float* x    = (const float*)d_in[0];
  const float* kern = (const float*)d_in[1];
  const float* bias = (const float*)d_in[2];
  const float* leaf = (const float*)d_in[3];
  // d_in[4] = route: topology hard-coded (perfect depth-5 tree, bit0=left)

  unsigned short* bws = (unsigned short*)d_ws;   // 100*4608 shorts = 921600 B

  prep_b<<<NTREES, 512, 0, stream>>>(kern, bias, bws);
  gbm_main<<<32768 / BM, 512, 0, stream>>>(x, bws, leaf, (float*)d_out);
}